// Round 5
// baseline (115.824 us; speedup 1.0000x reference)
//
#include <hip/hip_runtime.h>

// VQ-VAE forward + EMA update, MI355X.
// Sizes fixed by the reference: B=64, C=D=8, H=W=64, K=512.
constexpr int Kc   = 512;
constexpr int Dc   = 8;
constexpr int HWc  = 4096;            // 64*64
constexpr int CHWc = Dc * HWc;        // 32768
constexpr int Mc   = 64 * HWc;        // 262144 vectors
constexpr int TOTALc = Mc * Dc;       // 2097152 elements of z / z_q

typedef float v2f __attribute__((ext_vector_type(2)));

// 8 replica accumulators (one per XCD via blockIdx&7) to cut atomic contention.
constexpr int REP      = 8;
constexpr int RSTRIDE  = 4616;        // 512 counts + 4096 sums + 1 loss + 7 pad
constexpr int ACC_FLOATS = REP * RSTRIDE;   // 36928 floats (~148 KB)
// d_ws float layout:
//   [0 .. ACC_FLOATS)            replica accumulators (counts | sums | loss | pad) x8
//   [ACC_FLOATS .. +1024)        esq2[k] = {e_sq[k], 0} pairs (for packed-fma init)

__global__ __launch_bounds__(256) void vq_prep(const float* __restrict__ cb,
                                               float* __restrict__ ws) {
    const int tid = blockIdx.x * 256 + threadIdx.x;
    float4* w4 = (float4*)ws;
    for (int i = tid; i < ACC_FLOATS / 4; i += gridDim.x * 256)
        w4[i] = float4{0.f, 0.f, 0.f, 0.f};
    if (blockIdx.x == 0) {
        for (int k = threadIdx.x; k < Kc; k += 256) {
            float s = 0.f;
#pragma unroll
            for (int c = 0; c < Dc; ++c) {
                const float e = cb[k * Dc + c];
                s = fmaf(e, e, s);
            }
            ws[ACC_FLOATS + 2 * k]     = s;   // {esq, 0} pair
            ws[ACC_FLOATS + 2 * k + 1] = 0.f;
        }
    }
}

// 1024 blocks x 512 threads; block owns 256 consecutive vectors.
// Wave g = t>>6 scans codes [g*64, g*64+64) for all 256 vectors; each thread
// scores V=4 vectors (lane, lane+64, lane+128, lane+192) per codebook read.
// Inner product packed over c: 4 x v_pk_fma_f32 per (vector,k) + 1 hadd.
// 4 blocks/CU * 8 waves = 32 waves/CU.
__global__ __launch_bounds__(512, 8) void vq_main(const float* __restrict__ z,
                                                  const float* __restrict__ cb,
                                                  const float* __restrict__ esqw,
                                                  float* __restrict__ ws,
                                                  float* __restrict__ zq) {
    __shared__ float s_counts[Kc];
    __shared__ float s_sums[Kc * Dc];
    __shared__ float s_mn[8][256];
    __shared__ int   s_im[8][256];
    __shared__ float s_loss;

    const int t = threadIdx.x;
    for (int i = t; i < Kc; i += 512) s_counts[i] = 0.f;
    for (int i = t; i < Kc * Dc; i += 512) s_sums[i] = 0.f;
    if (t == 0) s_loss = 0.f;

    const int l = t & 63;
    // wave-uniform k-group; readfirstlane keeps codebook indices provably
    // uniform -> s_load (scalar) path for cb/esq2.
    const int g  = __builtin_amdgcn_readfirstlane(t >> 6);   // 0..7
    const int k0 = g << 6;

    const int base = blockIdx.x * 256;        // 256-aligned -> one batch idx
    const int n0 = (base + l) & (HWc - 1);
    const int b  = base >> 12;
    const float* zb = z + b * CHWc + n0;

    // zz[j][c] = -2*z for vectors l+64j, packed over c into float2 pairs.
    v2f zzp[4][4];
#pragma unroll
    for (int j = 0; j < 4; ++j)
#pragma unroll
        for (int p = 0; p < 4; ++p) {
            zzp[j][p].x = -2.0f * zb[(2 * p)     * HWc + 64 * j];
            zzp[j][p].y = -2.0f * zb[(2 * p + 1) * HWc + 64 * j];
        }

    const v2f* cb2  = (const v2f*)cb;         // row k = cb2[4k..4k+3]
    const v2f* esq2 = (const v2f*)esqw;       // {esq[k], 0}

    float mn[4] = {3.4e38f, 3.4e38f, 3.4e38f, 3.4e38f};
    int   im[4] = {k0, k0, k0, k0};
#pragma unroll 4
    for (int kk = 0; kk < 64; ++kk) {
        const int k = k0 + kk;
        const v2f e0 = cb2[k * 4 + 0];        // uniform -> s_load
        const v2f e1 = cb2[k * 4 + 1];
        const v2f e2 = cb2[k * 4 + 2];
        const v2f e3 = cb2[k * 4 + 3];
        const v2f eq = esq2[k];               // {esq, 0}
#pragma unroll
        for (int j = 0; j < 4; ++j) {
            v2f acc = zzp[j][0] * e0 + eq;    // -ffp-contract -> v_pk_fma_f32
            acc = zzp[j][1] * e1 + acc;
            acc = zzp[j][2] * e2 + acc;
            acc = zzp[j][3] * e3 + acc;
            const float a = acc.x + acc.y;    // score = esq - 2*dot
            const bool cm = a < mn[j];        // strict <: first index wins
            mn[j] = cm ? a : mn[j];
            im[j] = cm ? k : im[j];
        }
    }
#pragma unroll
    for (int j = 0; j < 4; ++j) {
        s_mn[g][l + 64 * j] = mn[j];
        s_im[g][l + 64 * j] = im[j];
    }
    __syncthreads();

    if (t < 256) {
        const int v = t;                      // block-local vector id
        float mnv = s_mn[0][v];
        int   imv = s_im[0][v];
#pragma unroll
        for (int gg = 1; gg < 8; ++gg) {
            const float m2 = s_mn[gg][v];     // groups ascending in k:
            const int   j2 = s_im[gg][v];     // strict < keeps first index
            const bool  c2 = m2 < mnv;
            mnv = c2 ? m2 : mnv;
            imv = c2 ? j2 : imv;
        }

        // Gather old-codebook row (16 KB table, L1-hot; 32B/lane).
        const float4* cb4 = (const float4*)cb;
        const float4 qa = cb4[imv * 2], qb = cb4[imv * 2 + 1];
        const float q[Dc] = {qa.x, qa.y, qa.z, qa.w, qb.x, qb.y, qb.z, qb.w};

        const int nv = (base + v) & (HWc - 1);
        const float* zv = z + b * CHWc + nv;  // re-read z (L1/L2-hot)
        float* zqv = zq + b * CHWc + nv;
        float lsum = 0.f;
        float zr[Dc];
#pragma unroll
        for (int c = 0; c < Dc; ++c) {
            zr[c] = zv[c * HWc];
            zqv[c * HWc] = q[c];              // coalesced stores
            const float d = q[c] - zr[c];
            lsum = fmaf(d, d, lsum);
        }

        // Per-block LDS histogram (ds_add_f32).
        unsafeAtomicAdd(&s_counts[imv], 1.0f);
#pragma unroll
        for (int c = 0; c < Dc; ++c)
            unsafeAtomicAdd(&s_sums[imv * Dc + c], zr[c]);
        unsafeAtomicAdd(&s_loss, lsum);
    }
    __syncthreads();

    // Flush non-zero bins to this block's replica accumulator (all 512 thr).
    float* acc = ws + (blockIdx.x & (REP - 1)) * RSTRIDE;
    for (int i = t; i < Kc; i += 512) {
        const float val = s_counts[i];
        if (val != 0.f) unsafeAtomicAdd(&acc[i], val);
    }
    for (int i = t; i < Kc * Dc; i += 512) {
        const float val = s_sums[i];
        if (val != 0.f) unsafeAtomicAdd(&acc[512 + i], val);
    }
    if (t == 0) unsafeAtomicAdd(&acc[4608], s_loss);
}

__global__ __launch_bounds__(512) void vq_final(const float* __restrict__ ws,
                                                const float* __restrict__ ema_cs,
                                                const float* __restrict__ ema_w,
                                                float* __restrict__ out) {
    constexpr float DEC  = 0.99f;
    constexpr float OMD  = (float)(1.0 - 0.99);      // matches jnp f32 cast
    constexpr float EPSf = 1e-5f;
    constexpr float KEPS = (float)(512 * 1e-5);      // 0.00512
    __shared__ float red[512];
    __shared__ float s_cs[512];

    const int t = threadIdx.x;   // 512 threads, 1 block
    // counts: lane-consecutive reads per replica (coalesced)
    float cnt = 0.f;
#pragma unroll
    for (int r = 0; r < REP; ++r) cnt += ws[r * RSTRIDE + t];
    const float ncs = ema_cs[t] * DEC + cnt * OMD;
    red[t] = ncs;
    __syncthreads();
    for (int s = 256; s > 0; s >>= 1) {
        if (t < s) red[t] += red[t + s];
        __syncthreads();
    }
    const float n  = red[0];
    const float cs = (ncs + EPSf) / (n + KEPS) * n;
    s_cs[t] = cs;

    float* out_loss = out + TOTALc;          // [1]
    float* out_cb   = out + TOTALc + 1;      // [K*D]
    float* out_cs   = out_cb + Kc * Dc;      // [K]
    float* out_nw   = out_cs + Kc;           // [K*D]

    out_cs[t] = cs;
    __syncthreads();

    // sums: fully coalesced element-major passes
    for (int e = t; e < Kc * Dc; e += 512) {
        float sm = 0.f;
#pragma unroll
        for (int r = 0; r < REP; ++r) sm += ws[r * RSTRIDE + 512 + e];
        const float nw = ema_w[e] * DEC + sm * OMD;
        out_nw[e] = nw;
        out_cb[e] = nw / s_cs[e >> 3];
    }
    if (t == 0) {
        float ls = 0.f;
#pragma unroll
        for (int r = 0; r < REP; ++r) ls += ws[r * RSTRIDE + 4608];
        out_loss[0] = ls * (1.0f / 2097152.0f);  // /2^21 exact
    }
}

extern "C" void kernel_launch(void* const* d_in, const int* in_sizes, int n_in,
                              void* d_out, int out_size, void* d_ws, size_t ws_size,
                              hipStream_t stream) {
    const float* z      = (const float*)d_in[0];
    const float* cb     = (const float*)d_in[1];
    const float* ema_cs = (const float*)d_in[2];
    const float* ema_w  = (const float*)d_in[3];
    float* out = (float*)d_out;
    float* ws  = (float*)d_ws;

    vq_prep<<<32, 256, 0, stream>>>(cb, ws);
    vq_main<<<Mc / 256, 512, 0, stream>>>(z, cb, ws + ACC_FLOATS, ws, out);
    vq_final<<<1, 512, 0, stream>>>(ws, ema_cs, ema_w, out);
}